// Round 11
// baseline (2246.486 us; speedup 1.0000x reference)
//
#include <hip/hip_runtime.h>
#include <hip/hip_bf16.h>
#include <math.h>

typedef __hip_bfloat16 bf16;
typedef _Float16 f16;
typedef _Float16 f16x2 __attribute__((ext_vector_type(2)));
typedef _Float16 f16x8 __attribute__((ext_vector_type(8)));
typedef float f32x4 __attribute__((ext_vector_type(4)));

struct Sched { int tt[5]; int fi[5]; int jj[5]; };
struct CvtF32 { const void* src[4]; float* dst[4]; int n[4]; int blk0[5]; };
struct CvtF16 { const void* src[6]; f16* dst[6]; int n[6]; int blk0[7]; };
struct W2J { const void* wd[5]; const void* wf[5]; f16* dst[5]; int mid[5]; int cin[5]; int n[5]; int blk0[6]; };

// ---------------------------------------------------------------- dtype detect + zero sums (fused)
__global__ void k_detect(const unsigned int* __restrict__ w, int nwords, int* __restrict__ flag,
                         float* __restrict__ zp, int zn){
  if(blockIdx.x==0){
    __shared__ int cnt;
    if(threadIdx.x==0) cnt=0;
    __syncthreads();
    int local=0;
    for(int i=threadIdx.x;i<nwords;i+=256){
      unsigned int v=w[i];
      int e=(v>>7)&0xFF;
      if(e>=0xC0) local++;
    }
    atomicAdd(&cnt, local);
    __syncthreads();
    if(threadIdx.x==0) flag[0] = (cnt > (nwords>>3)) ? 1 : 0;
  } else {
    int i=(blockIdx.x-1)*256+threadIdx.x;
    if(i<zn) zp[i]=0.f;
  }
}

__device__ inline float ldmix(const void* p, size_t i, bool f32m){
  return f32m ? ((const float*)p)[i] : __bfloat162float(((const bf16*)p)[i]);
}

// ---------------------------------------------------------------- Round-16: FPS_0 merged with ALL converts
// [ FPS layer 0 (128 blocks, proven body; stages via ldmix from raw input)
//   || f32 converts || f16 converts (t5 written TRANSPOSED -> t5T for W')
//   || w2all ]
__global__ __launch_bounds__(256) void k_fps0m(
    const void* __restrict__ xyzRaw, float* __restrict__ anchors,
    CvtF32 J32, CvtF16 J16, W2J JW, const int* __restrict__ flag, int c32B, int c16B)
{
  __shared__ float4 ptsS[8*256];
  __shared__ unsigned long long keyS[2][4];
  __shared__ float ancS[3*1024];
  int bid=(int)blockIdx.x;
  if(bid<128){
    const int L=4, N=2048, m=1024, T=4;
    bool f32m=*flag!=0;
    int prob=bid;
    int b=prob/T, tt=prob%T;
    int f=tt;
    size_t srcOff = ((size_t)(b*L+f))*N*3;
    float* anc = anchors + ((size_t)(b*T+tt))*m*3;
    int tid=threadIdx.x;
    for(int t=tid;t<N;t+=256)
      ptsS[t]=make_float4(ldmix(xyzRaw,srcOff+3*t,f32m),ldmix(xyzRaw,srcOff+3*t+1,f32m),ldmix(xyzRaw,srcOff+3*t+2,f32m),0.f);
    __syncthreads();
    float px[8],py[8],pz[8],mind[8];
#pragma unroll
    for(int j=0;j<8;j++){
      float4 v=ptsS[tid+j*256];
      px[j]=v.x; py[j]=v.y; pz[j]=v.z; mind[j]=1e10f;
    }
    float4 p0=ptsS[0];
    float lx=p0.x, ly=p0.y, lz=p0.z;
    if(tid==0){ ancS[0]=lx; ancS[1]=ly; ancS[2]=lz; }
    int w=tid>>6;
    for(int it=1; it<m; ++it){
      float bv=-1.f; int bi=0;
#pragma unroll
      for(int j=0;j<8;j++){
#pragma clang fp contract(off)
        float dx=px[j]-lx, dy=py[j]-ly, dz=pz[j]-lz;
        float d2=dx*dx+dy*dy+dz*dz;
        float mv=mind[j]; if(d2<mv) mv=d2; mind[j]=mv;
        if(mv>bv){ bv=mv; bi=tid+j*256; }
      }
      unsigned int hi=__float_as_uint(bv);
      unsigned int lo=0xFFFFFFFFu-(unsigned)bi;
#define DPPSTEP(CTRL) { \
      unsigned int shi=(unsigned)__builtin_amdgcn_update_dpp(0,(int)hi,CTRL,0xF,0xF,true); \
      unsigned int slo=(unsigned)__builtin_amdgcn_update_dpp(0,(int)lo,CTRL,0xF,0xF,true); \
      bool g=(shi>hi)||(shi==hi&&slo>lo); \
      hi=g?shi:hi; lo=g?slo:lo; }
      DPPSTEP(0x111) DPPSTEP(0x112) DPPSTEP(0x114) DPPSTEP(0x118) DPPSTEP(0x142) DPPSTEP(0x143)
#undef DPPSTEP
      if((tid&63)==63)
        keyS[it&1][w]=((unsigned long long)hi<<32)|lo;
      __syncthreads();
      unsigned long long k0=keyS[it&1][0], k1=keyS[it&1][1];
      unsigned long long k2=keyS[it&1][2], k3=keyS[it&1][3];
      unsigned long long ka = k0>k1?k0:k1;
      unsigned long long kb = k2>k3?k2:k3;
      unsigned long long kk = ka>kb?ka:kb;
      int wi = (int)(0xFFFFFFFFu - (unsigned)(kk & 0xFFFFFFFFull));
      float4 wc = ptsS[wi];
      lx=wc.x; ly=wc.y; lz=wc.z;
      if(tid==0){ ancS[3*it]=lx; ancS[3*it+1]=ly; ancS[3*it+2]=lz; }
    }
    __syncthreads();
    for(int t=tid;t<3*m;t+=256) anc[t]=ancS[t];
  } else if(bid < 128+c32B){
    int b=bid-128;
    int j=0;
    while(j<3 && J32.blk0[j+1]<=b) j++;
    int i=(b-J32.blk0[j])*256+threadIdx.x;
    if(i>=J32.n[j]) return;
    bool f32m=*flag!=0;
    J32.dst[j][i]=ldmix(J32.src[j],i,f32m);
  } else if(bid < 128+c32B+c16B){
    int b=bid-128-c32B;
    int j=0;
    while(j<5 && J16.blk0[j+1]<=b) j++;
    int i=(b-J16.blk0[j])*256+threadIdx.x;
    if(i>=J16.n[j]) return;
    bool f32m=*flag!=0;
    float v=ldmix(J16.src[j],i,f32m);
    if(j==4){
      // t5 [2048][1536] -> t5T [1536][2048] (transposed for the W' GEMM)
      int o=i/1536, c=i-o*1536;
      J16.dst[4][(size_t)c*2048+o]=(f16)v;
    } else {
      J16.dst[j][i]=(f16)v;
    }
  } else {
    int b=bid-128-c32B-c16B;
    int j=0;
    while(j<4 && JW.blk0[j+1]<=b) j++;
    int i=(b-JW.blk0[j])*256+threadIdx.x;
    if(i>=JW.n[j]) return;
    int cin=JW.cin[j]; int K3=3*cin;
    int o=i/K3; int rem=i-o*K3; int a=rem/cin; int c=rem-a*cin;
    float v=0.f;
    if(o<JW.mid[j]){
      bool f32m=*flag!=0;
      v=ldmix(JW.wd[j],(size_t)3*o+a,f32m)*ldmix(JW.wf[j],(size_t)o*cin+c,f32m);
    }
    JW.dst[j][i]=(f16)v;
  }
}

// ---------------------------------------------------------------- 3-way merged kernel (+ optional W' GEMM branch, WB)
// [ FPS (layer lf) || outer/part0 (layer lo) || bq (layer lb) || W'=fcw@t5T ]
// WB only instantiated true for mega_pre (extra 20KB LDS would hurt rider
// occupancy in the other megas).
template<int P, bool WB>
__global__ __launch_bounds__(256) void k_mega(
    const float* __restrict__ xyzF, int Lf, int Nf, int mf,
    int c0,int c1,int c2,int c3, int Tf, float* __restrict__ ancOut, int fpsN,
    int oN, int isP0,
    const f16* __restrict__ featsO, const float* __restrict__ XinO, const float* __restrict__ XoutO,
    const int* __restrict__ bqO, f16* __restrict__ GoN, int mO, int cinO, int NO, int LinO,
    size_t aBSO, int MO, Sched SO, const float* __restrict__ WdO, int midO, int ldO,
    const float* __restrict__ XinB, const float* __restrict__ XoutB, int* __restrict__ bqOut,
    int NB, int mB, float r2B, int LinB, size_t aBSB, int MB, Sched SB, int chunksB, int bqN,
    const f16* __restrict__ wA, const f16* __restrict__ wB, f16* __restrict__ wO)
{
  __shared__ float4 ptsS[P*256];
  __shared__ unsigned long long keyS[2][4];
  __shared__ float sp[768];
  __shared__ f16 AsW[WB?128*40:1];
  __shared__ f16 BsW[WB?128*40:1];
  int bid=(int)blockIdx.x;
  if(bid < fpsN){
    int prob=bid;
    int b=prob/Tf, tt=prob%Tf;
    int f=(tt==0)?c0:(tt==1)?c1:(tt==2)?c2:c3;
    const float* src = xyzF + ((size_t)(b*Lf+f))*Nf*3;
    float* anc = ancOut + ((size_t)(b*Tf+tt))*mf*3;
    int tid=threadIdx.x;
    for(int t=tid;t<Nf;t+=256)
      ptsS[t]=make_float4(src[3*t],src[3*t+1],src[3*t+2],0.f);
    __syncthreads();
    float px[P],py[P],pz[P],mind[P];
#pragma unroll
    for(int j=0;j<P;j++){
      float4 v=ptsS[tid+j*256];
      px[j]=v.x; py[j]=v.y; pz[j]=v.z; mind[j]=1e10f;
    }
    float4 p0=ptsS[0];
    float lx=p0.x, ly=p0.y, lz=p0.z;
    if(tid==0){ anc[0]=lx; anc[1]=ly; anc[2]=lz; }
    int w=tid>>6;
    for(int it=1; it<mf; ++it){
      float bv=-1.f; int bi=0;
#pragma unroll
      for(int j=0;j<P;j++){
#pragma clang fp contract(off)
        float dx=px[j]-lx, dy=py[j]-ly, dz=pz[j]-lz;
        float d2=dx*dx+dy*dy+dz*dz;
        float mv=mind[j]; if(d2<mv) mv=d2; mind[j]=mv;
        if(mv>bv){ bv=mv; bi=tid+j*256; }
      }
      unsigned int hi=__float_as_uint(bv);
      unsigned int lo=0xFFFFFFFFu-(unsigned)bi;
#define DPPSTEP(CTRL) { \
      unsigned int shi=(unsigned)__builtin_amdgcn_update_dpp(0,(int)hi,CTRL,0xF,0xF,true); \
      unsigned int slo=(unsigned)__builtin_amdgcn_update_dpp(0,(int)lo,CTRL,0xF,0xF,true); \
      bool g=(shi>hi)||(shi==hi&&slo>lo); \
      hi=g?shi:hi; lo=g?slo:lo; }
      DPPSTEP(0x111) DPPSTEP(0x112) DPPSTEP(0x114) DPPSTEP(0x118) DPPSTEP(0x142) DPPSTEP(0x143)
#undef DPPSTEP
      if((tid&63)==63)
        keyS[it&1][w]=((unsigned long long)hi<<32)|lo;
      __syncthreads();
      unsigned long long k0=keyS[it&1][0], k1=keyS[it&1][1];
      unsigned long long k2=keyS[it&1][2], k3=keyS[it&1][3];
      unsigned long long ka = k0>k1?k0:k1;
      unsigned long long kb = k2>k3?k2:k3;
      unsigned long long kk = ka>kb?ka:kb;
      int wi = (int)(0xFFFFFFFFu - (unsigned)(kk & 0xFFFFFFFFull));
      float4 wc = ptsS[wi];
      lx=wc.x; ly=wc.y; lz=wc.z;
      if(tid==0){ anc[3*it]=lx; anc[3*it+1]=ly; anc[3*it+2]=lz; }
    }
  } else if(bid < fpsN + oN){
    int ob = bid - fpsN;
    if(isP0){
      int quarter = MO>>2;
      int tt = ob / quarter, rb = ob - tt*quarter;
      int sub = threadIdx.x>>6;
      int o = threadIdx.x&63;
      int row = rb*4 + sub;
      int b = row/mO, mm = row - b*mO;
      const float* A = XoutO + (size_t)b*aBSO + (size_t)tt*mO*3 + (size_t)mm*3;
      float ax=A[0], ay=A[1], az=A[2];
      float w0=0,w1=0,w2=0;
      if(o<midO){ w0=WdO[3*o]; w1=WdO[3*o+1]; w2=WdO[3*o+2]; }
      int fr=SO.fi[tt];
      int nmask=NO-1;
      const int* id = bqO + ((size_t)tt*MO + row)*9;
      const float* Pb = XinO + ((size_t)b*LinO+fr)*(size_t)NO*3;
      float acc=0.f;
      for(int k=0;k<9;k++){
        int p=id[k] & nmask;
        const float* q = Pb + (size_t)p*3;
        float dx=q[0]-ax, dy=q[1]-ay, dz=q[2]-az;
        acc += dx*w0+dy*w1+dz*w2;
      }
      if(o<midO) GoN[(size_t)tt*MO*ldO + (size_t)row*ldO + o] = (f16)acc;
    } else {
      int cw2 = cinO>>1; if(cw2>256) cw2=256;
      int rpb = 256/cw2;
      int tid=threadIdx.x;
      int sub=tid/cw2, lc=tid-sub*cw2;
      int r=ob*rpb+sub;
      int Kp=3*cinO;
      int nmask=NO-1;
      int s=r/MO, mrow=r-s*MO;
      int b=mrow/mO, mm=mrow-b*mO;
      int tt=SO.tt[s], fr=SO.fi[s];
      const float* A0=XoutO+(size_t)b*aBSO+(size_t)tt*mO*3+(size_t)mm*3;
      float ax=A0[0],ay=A0[1],az=A0[2];
      const float* Pb=XinO+((size_t)b*LinO+fr)*(size_t)NO*3;
      const f16* Fb=featsO+(((size_t)b*LinO+fr)*(size_t)NO)*(size_t)cinO;
      const int* id=bqO+(size_t)r*9;
      int idx[9]; float d0[9],d1[9],d2a[9];
#pragma unroll
      for(int k=0;k<9;k++){
        int p=id[k]&nmask; idx[k]=p;
        const float* q=Pb+(size_t)p*3;
        d0[k]=q[0]-ax; d1[k]=q[1]-ay; d2a[k]=q[2]-az;
      }
      f16* Gr=GoN+(size_t)r*Kp;
      for(int cc=2*lc; cc<cinO; cc+=2*cw2){
        float a0=0,a1=0,a2=0,b0=0,b1=0,b2=0;
#pragma unroll
        for(int k=0;k<9;k++){
          f16x2 fv=*(const f16x2*)(Fb+(size_t)idx[k]*cinO+cc);
          float f0=(float)fv[0], f1=(float)fv[1];
          a0=fmaf(d0[k],f0,a0); b0=fmaf(d0[k],f1,b0);
          a1=fmaf(d1[k],f0,a1); b1=fmaf(d1[k],f1,b1);
          a2=fmaf(d2a[k],f0,a2); b2=fmaf(d2a[k],f1,b2);
        }
        f16x2 o0={(f16)a0,(f16)b0}, o1={(f16)a1,(f16)b1}, o2={(f16)a2,(f16)b2};
        *(f16x2*)(Gr+cc)=o0; *(f16x2*)(Gr+cinO+cc)=o1; *(f16x2*)(Gr+2*cinO+cc)=o2;
      }
    }
  } else if(bid < fpsN + oN + bqN){
    int fb=bid-fpsN-oN;
    int s=fb/(32*chunksB);
    int rem=fb-s*(32*chunksB);
    int b=rem/chunksB;
    int a=(rem-b*chunksB)*256+threadIdx.x;
    int tt=SB.tt[s], fr=SB.fi[s];
    const float* Pb = XinB + ((size_t)b*LinB + fr)*(size_t)NB*3;
    bool act = a<mB;
    float ax=0,ay=0,az=0;
    int* o = bqOut + ((size_t)s*MB + (size_t)b*mB + (size_t)(act?a:0))*9;
    if(act){
      const float* A=XoutB+(size_t)b*aBSB+(size_t)tt*mB*3+(size_t)a*3;
      ax=A[0]; ay=A[1]; az=A[2];
    }
    int cnt = act?0:9, first=0;
    for(int base=0; base<NB; base+=256){
      for(int t=threadIdx.x; t<768; t+=256) sp[t]=Pb[(size_t)base*3+t];
      __syncthreads();
      for(int q=0;q<256;q++){
#pragma clang fp contract(off)
        float dx=sp[3*q]-ax, dy=sp[3*q+1]-ay, dz=sp[3*q+2]-az;
        float d2=dx*dx+dy*dy+dz*dz;
        if(d2<r2B && cnt<9){
          int p=base+q;
          if(cnt==0) first=p;
          o[cnt]=p; cnt++;
        }
      }
      if(__syncthreads_and(cnt>=9)) break;
    }
    if(act){ for(int k=cnt;k<9;k++) o[k]=first; }
  } else if(WB){
    // ---------------- W' = fcw @ t5T^T  (M=1024, N=1536, K=2048), plain 128x128 f16 MFMA GEMM
    int wb = bid - fpsN - oN - bqN;
    if(wb>=96) return;
    int rowBase=(wb/12)*128, colBase=(wb%12)*128;
    int tid=threadIdx.x;
    int lane=tid&63, w=tid>>6;
    int quad=lane>>4, l15=lane&15;
    int rowOff=(w>>1)*64, colOff=(w&1)*64;
    f32x4 acc[4][4];
#pragma unroll
    for(int i=0;i<4;i++)
#pragma unroll
      for(int j=0;j<4;j++) acc[i][j]=(f32x4){0.f,0.f,0.f,0.f};
    const int Kp=2048;
    int srow=tid>>1, shalf=tid&1;
    for(int ct=0;ct<Kp>>5;ct++){
      __syncthreads();
      {
        const uint4* s=(const uint4*)(wA+(size_t)(rowBase+srow)*Kp+(ct<<5)+(shalf<<4));
        uint4 u0=s[0], u1=s[1];
        *(uint4*)(AsW + srow*40 + (shalf<<4))     = u0;
        *(uint4*)(AsW + srow*40 + (shalf<<4) + 8) = u1;
      }
      {
        const uint4* s=(const uint4*)(wB+(size_t)(colBase+srow)*Kp+(ct<<5)+(shalf<<4));
        uint4 u0=s[0], u1=s[1];
        *(uint4*)(BsW + srow*40 + (shalf<<4))     = u0;
        *(uint4*)(BsW + srow*40 + (shalf<<4) + 8) = u1;
      }
      __syncthreads();
      f16x8 af[4], bf4[4];
#pragma unroll
      for(int rt=0;rt<4;rt++) af[rt]=*(const f16x8*)(AsW + (rowOff+rt*16+l15)*40 + quad*8);
#pragma unroll
      for(int ctl=0;ctl<4;ctl++) bf4[ctl]=*(const f16x8*)(BsW + (colOff+ctl*16+l15)*40 + quad*8);
#pragma unroll
      for(int rt=0;rt<4;rt++)
#pragma unroll
        for(int ctl=0;ctl<4;ctl++)
          acc[rt][ctl]=__builtin_amdgcn_mfma_f32_16x16x32_f16(af[rt],bf4[ctl],acc[rt][ctl],0,0,0);
    }
#pragma unroll
    for(int rt=0;rt<4;rt++)
#pragma unroll
      for(int r=0;r<4;r++){
        int row=rowBase+rowOff+rt*16+quad*4+r;
#pragma unroll
        for(int ctl=0;ctl<4;ctl++){
          int col=colBase+colOff+ctl*16+l15;
          wO[(size_t)row*1536+col]=(f16)acc[rt][ctl][r];
        }
      }
  }
}

// ---------------------------------------------------------------- G[r, a*cin+c] standalone (layer 5 only)
__global__ __launch_bounds__(256) void k_outer(
    const f16* __restrict__ feats, const float* __restrict__ Xin,
    const float* __restrict__ Xout, const int* __restrict__ bqAll,
    f16* __restrict__ Gh, int m, int cin, int N, int Lin,
    size_t aBS, int nmask, int M, Sched S)
{
  int cw2 = cin>>1; if(cw2>256) cw2=256;
  int rpb = 256/cw2;
  int tid=threadIdx.x;
  int sub=tid/cw2, lc=tid-sub*cw2;
  int r=blockIdx.x*rpb+sub;
  int Kp=3*cin;
  int s=r/M, mrow=r-s*M;
  int b=mrow/m, mm=mrow-b*m;
  int tt=S.tt[s], fr=S.fi[s];
  const float* A0=Xout+(size_t)b*aBS+(size_t)tt*m*3+(size_t)mm*3;
  float ax=A0[0],ay=A0[1],az=A0[2];
  const float* Pb=Xin+((size_t)b*Lin+fr)*(size_t)N*3;
  const f16* Fb=feats+(((size_t)b*Lin+fr)*(size_t)N)*(size_t)cin;
  const int* id=bqAll+(size_t)r*9;
  int idx[9]; float d0[9],d1[9],d2a[9];
#pragma unroll
  for(int k=0;k<9;k++){
    int p=id[k]&nmask; idx[k]=p;
    const float* q=Pb+(size_t)p*3;
    d0[k]=q[0]-ax; d1[k]=q[1]-ay; d2a[k]=q[2]-az;
  }
  f16* Gr=Gh+(size_t)r*Kp;
  for(int cc=2*lc; cc<cin; cc+=2*cw2){
    float a0=0,a1=0,a2=0,b0=0,b1=0,b2=0;
#pragma unroll
    for(int k=0;k<9;k++){
      f16x2 fv=*(const f16x2*)(Fb+(size_t)idx[k]*cin+cc);
      float f0=(float)fv[0], f1=(float)fv[1];
      a0=fmaf(d0[k],f0,a0); b0=fmaf(d0[k],f1,b0);
      a1=fmaf(d1[k],f0,a1); b1=fmaf(d1[k],f1,b1);
      a2=fmaf(d2a[k],f0,a2); b2=fmaf(d2a[k],f1,b2);
    }
    f16x2 o0={(f16)a0,(f16)b0}, o1={(f16)a1,(f16)b1}, o2={(f16)a2,(f16)b2};
    *(f16x2*)(Gr+cc)=o0; *(f16x2*)(Gr+cin+cc)=o1; *(f16x2*)(Gr+2*cin+cc)=o2;
  }
}

// ---------------------------------------------------------------- pair GEMM + fused BN stats
__global__ __launch_bounds__(256) void k_pg(
    const f16* __restrict__ Gh, const f16* __restrict__ W2,
    f16* __restrict__ nfh, int Kp, int mid, int C, int M, Sched S,
    float* __restrict__ sumsL, int sumStride)
{
  __shared__ f16 As[128*40];
  __shared__ f16 Bs[128*40];
  int tid=threadIdx.x;
  int lane=tid&63, w=tid>>6;
  int quad=lane>>4, l15=lane&15;
  int rowOff=(w>>1)*64, colOff=(w&1)*64;
  int rowBase=blockIdx.x*128, colBase=blockIdx.y*128;
  f32x4 acc[4][4];
#pragma unroll
  for(int i=0;i<4;i++)
#pragma unroll
    for(int j=0;j<4;j++) acc[i][j]=(f32x4){0.f,0.f,0.f,0.f};
  int nct=Kp>>5;
  int srow=tid>>1, shalf=tid&1;
  for(int ct=0;ct<nct;ct++){
    __syncthreads();
    {
      const uint4* s=(const uint4*)(Gh+(size_t)(rowBase+srow)*Kp+(ct<<5)+(shalf<<4));
      uint4 u0=s[0], u1=s[1];
      *(uint4*)(As + srow*40 + (shalf<<4))     = u0;
      *(uint4*)(As + srow*40 + (shalf<<4) + 8) = u1;
    }
    {
      const uint4* s=(const uint4*)(W2+(size_t)(colBase+srow)*Kp+(ct<<5)+(shalf<<4));
      uint4 u0=s[0], u1=s[1];
      *(uint4*)(Bs + srow*40 + (shalf<<4))     = u0;
      *(uint4*)(Bs + srow*40 + (shalf<<4) + 8) = u1;
    }
    __syncthreads();
    f16x8 af[4], bf4[4];
#pragma unroll
    for(int rt=0;rt<4;rt++) af[rt]=*(const f16x8*)(As + (rowOff+rt*16+l15)*40 + quad*8);
#pragma unroll
    for(int ctl=0;ctl<4;ctl++) bf4[ctl]=*(const f16x8*)(Bs + (colOff+ctl*16+l15)*40 + quad*8);
#pragma unroll
    for(int rt=0;rt<4;rt++)
#pragma unroll
      for(int ctl=0;ctl<4;ctl++)
        acc[rt][ctl]=__builtin_amdgcn_mfma_f32_16x16x32_f16(af[rt],bf4[ctl],acc[rt][ctl],0,0,0);
  }
  int s0=rowBase/M;
  int tt0=S.tt[s0], j0=S.jj[s0];
#pragma unroll
  for(int ctl=0;ctl<4;ctl++){
    int gcol=colBase+colOff+ctl*16+l15;
    float cs=0.f, cq=0.f;
#pragma unroll
    for(int rt=0;rt<4;rt++)
#pragma unroll
      for(int r=0;r<4;r++){
        float v=(float)(f16)acc[rt][ctl][r];
        cs+=v; cq+=v*v;
      }
    cs+=__shfl_xor(cs,16); cq+=__shfl_xor(cq,16);
    cs+=__shfl_xor(cs,32); cq+=__shfl_xor(cq,32);
    if(quad==0 && gcol<mid){
      atomicAdd(&sumsL[tt0*sumStride + j0*mid + gcol], cs);
      atomicAdd(&sumsL[tt0*sumStride + C + j0*mid + gcol], cq);
    }
  }
#pragma unroll
  for(int rt=0;rt<4;rt++){
#pragma unroll
    for(int r=0;r<4;r++){
      int row=rowBase+rowOff+rt*16+quad*4+r;
      int s=row/M, mrow=row-s*M;
      int tt=S.tt[s], j=S.jj[s];
      f16* base = nfh + (size_t)tt*M*C + (size_t)mrow*C + j*mid;
#pragma unroll
      for(int ctl=0;ctl<4;ctl++){
        int col=colBase+colOff+ctl*16+l15;
        if(col<mid) base[col]=(f16)acc[rt][ctl][r];
      }
    }
  }
}

// ---------------------------------------------------------------- BN stats (layer 0 only)
__global__ void k_bnstat(const f16* __restrict__ nfh, int M, int C, float* __restrict__ sumsL,
                         int mid, int4 jm, int sumStride){
  int c = blockIdx.x*256 + threadIdx.x;
  if(c>=C) return;
  int tt=blockIdx.z;
  int jmask = (tt==0)?jm.x:(tt==1)?jm.y:(tt==2)?jm.z:jm.w;
  int j=c/mid;
  if(!((jmask>>j)&1)) return;
  const f16* base=nfh+(size_t)tt*M*C;
  int rows = M>>5;
  int r0 = blockIdx.y*rows, r1 = r0+rows;
  float s=0.f, s2=0.f;
  for(int r=r0;r<r1;r++){
    float v=(float)base[(size_t)r*C+c];
    s+=v; s2+=v*v;
  }
  atomicAdd(&sumsL[tt*sumStride+c], s);
  atomicAdd(&sumsL[tt*sumStride+C+c], s2);
}

// ---------------------------------------------------------------- MFMA GEMM, BN finalize fused
template<bool RELU, bool DYN, bool BNA>
__global__ __launch_bounds__(256) void k_gemm_mfma(
    const f16* __restrict__ Ag, const f16* __restrict__ Bh,
    const float* __restrict__ bias, void* __restrict__ out,
    int K, int N, int mloc, size_t oBS, size_t ttA, size_t ttO,
    const int* __restrict__ oflag, const float* __restrict__ sumsAll, int sumStride, float invM)
{
  __shared__ f16 As[128*40];
  __shared__ f16 Bs[128*40];
  __shared__ float scbL[BNA?2*2304:2];
  int tid=threadIdx.x;
  int lane=tid&63, w=tid>>6;
  int quad=lane>>4, l15=lane&15;
  int rowOff=(w>>1)*64, colOff=(w&1)*64;
  int rowBase=blockIdx.x*128, colBase=blockIdx.y*128;
  int tt=blockIdx.z;
  const f16* A0=Ag+(size_t)tt*ttA;
  if(BNA){
    const float* sm=sumsAll+(size_t)tt*sumStride;
    for(int c=tid;c<K;c+=256){
      float s1=sm[c], s2=sm[K+c];
      float mean=s1*invM;
      float var=s2*invM-mean*mean; if(var<0.f) var=0.f;
      float rs=(s2==0.f)?0.f:(1.0f/sqrtf(var+1e-5f));
      scbL[c]=rs; scbL[K+c]=-mean*rs;
    }
  }
  f32x4 acc[4][4];
#pragma unroll
  for(int i=0;i<4;i++)
#pragma unroll
    for(int j=0;j<4;j++) acc[i][j]=(f32x4){0.f,0.f,0.f,0.f};
  int nct=K>>5;
  int srow=tid>>1, shalf=tid&1;
  for(int ct=0;ct<nct;ct++){
    __syncthreads();
    {
      int c0g=(ct<<5)+(shalf<<4);
      const f16* src=A0+(size_t)(rowBase+srow)*K+c0g;
      if(BNA){
        f16x8 x0=((const f16x8*)src)[0], x1=((const f16x8*)src)[1];
        f16x8 h0,h1;
#pragma unroll
        for(int q=0;q<8;q++){
          h0[q]=(f16)fmaxf(fmaf((float)x0[q],scbL[c0g+q],scbL[K+c0g+q]),0.f);
          h1[q]=(f16)fmaxf(fmaf((float)x1[q],scbL[c0g+8+q],scbL[K+c0g+8+q]),0.f);
        }
        *(f16x8*)(As+srow*40+(shalf<<4))=h0;
        *(f16x8*)(As+srow*40+(shalf<<4)+8)=h1;
      } else {
        const uint4* s=(const uint4*)src;
        uint4 u0=s[0],u1=s[1];
        *(uint4*)(As+srow*40+(shalf<<4))=u0;
        *(uint4*)(As+srow*40+(shalf<<4)+8)=u1;
      }
    }
    {
      const uint4* s=(const uint4*)(Bh+(size_t)(colBase+srow)*K+(ct<<5)+(shalf<<4));
      uint4 u0=s[0], u1=s[1];
      *(uint4*)(Bs + srow*40 + (shalf<<4))     = u0;
      *(uint4*)(Bs + srow*40 + (shalf<<4) + 8) = u1;
    }
    __syncthreads();
    f16x8 af[4], bf4[4];
#pragma unroll
    for(int rt=0;rt<4;rt++) af[rt]=*(const f16x8*)(As + (rowOff+rt*16+l15)*40 + quad*8);
#pragma unroll
    for(int ctl=0;ctl<4;ctl++) bf4[ctl]=*(const f16x8*)(Bs + (colOff+ctl*16+l15)*40 + quad*8);
#pragma unroll
    for(int rt=0;rt<4;rt++)
#pragma unroll
      for(int ctl=0;ctl<4;ctl++)
        acc[rt][ctl]=__builtin_amdgcn_mfma_f32_16x16x32_f16(af[rt],bf4[ctl],acc[rt][ctl],0,0,0);
  }
  bool f32m = DYN ? (*oflag!=0) : true;
#pragma unroll
  for(int rt=0;rt<4;rt++){
#pragma unroll
    for(int r=0;r<4;r++){
      int row=rowBase+rowOff+rt*16+quad*4+r;
      int rb=row/mloc, rm=row-rb*mloc;
      size_t obase=(size_t)rb*oBS + (size_t)tt*ttO + (size_t)rm*N;
#pragma unroll
      for(int ctl=0;ctl<4;ctl++){
        int col=colBase+colOff+ctl*16+l15;
        float v=acc[rt][ctl][r];
        if(bias) v+=bias[col];
        if(RELU) v=fmaxf(v,0.f);
        if(DYN){
          if(!f32m) ((bf16*)out)[obase+col]=__float2bfloat16(v);
          else      ((float*)out)[obase+col]=v;
        } else {
          ((f16*)out)[obase+col]=(f16)v;
        }
      }
    }
  }
}

// ---------------------------------------------------------------- f32 GEMM (layer 0 temporal, K=45), BN finalize fused
__global__ __launch_bounds__(256) void k_gemm0(
    const f16* __restrict__ nfh, const float* __restrict__ Wg,
    f16* __restrict__ out, int M, int K, int N, int mloc, size_t oBS, size_t ttO,
    const float* __restrict__ sumsAll, int sumStride, float invM)
{
  __shared__ alignas(16) float As[16][64];
  __shared__ alignas(16) float Bs[16][64];
  __shared__ float scbL[128];
  int tid=threadIdx.x, tx=tid&15, ty=tid>>4;
  int rowBase=blockIdx.x*64, colBase=blockIdx.y*64;
  int tt=blockIdx.z;
  const f16* A0=nfh+(size_t)tt*M*K;
  {
    const float* sm=sumsAll+(size_t)tt*sumStride;
    for(int c=tid;c<K;c+=256){
      float s1=sm[c], s2=sm[K+c];
      float mean=s1*invM;
      float var=s2*invM-mean*mean; if(var<0.f) var=0.f;
      float rs=(s2==0.f)?0.f:(1.0f/sqrtf(var+1e-5f));
      scbL[c]=rs; scbL[K+c]=-mean*rs;
    }
  }
  float acc[4][4];
#pragma unroll
  for(int i=0;i<4;i++)
#pragma unroll
    for(int j=0;j<4;j++) acc[i][j]=0.f;
  int lrow=tid&63, lcq=tid>>6;
  int nct=(K+15)>>4;
  for(int ct=0;ct<nct;ct++){
    __syncthreads();
    {
      int r=rowBase+lrow, c0=(ct<<4)+(lcq<<2);
#pragma unroll
      for(int q=0;q<4;q++){
        int c=c0+q;
        As[(lcq<<2)+q][lrow] = (c<K)? fmaxf(fmaf((float)A0[(size_t)r*K+c],scbL[c],scbL[K+c]),0.f) : 0.f;
      }
    }
    {
      int og=colBase+lrow, c0=(ct<<4)+(lcq<<2);
#pragma unroll
      for(int q=0;q<4;q++){
        int c=c0+q;
        Bs[(lcq<<2)+q][lrow] = (c<K)? Wg[(size_t)og*K+c] : 0.f;
      }
    }
    __syncthreads();
#pragma unroll
    for(int c=0;c<16;c++){
      float4 a4=*(const float4*)&As[c][ty<<2];
      float av[4]={a4.x,a4.y,a4.z,a4.w};
      float4 b4=*(const float4*)&Bs[c][tx<<2];
      float bw[4]={b4.x,b4.y,b4.z,b4.w};
#pragma unroll
      for(int i=0;i<4;i++)
#pragma unroll
        for(int j=0;j<4;j++) acc[i][j]+=av[i]*bw[j];
    }
  }
#pragma unroll
  for(int i=0;i<4;i++){
    int r=rowBase+(ty<<2)+i;
    int rb=r/mloc, rm=r-rb*mloc;
    size_t obase=(size_t)rb*oBS + (size_t)blockIdx.z*ttO + (size_t)rm*N;
#pragma unroll
    for(int j=0;j<4;j++){
      int o=colBase+(tx<<2)+j;
      out[obase+o]=(f16)fmaxf(acc[i][j],0.f);
    }
  }
}

// ---------------------------------------------------------------- host
extern "C" void kernel_launch(void* const* d_in, const int* in_sizes, int n_in,
                              void* d_out, int out_size, void* d_ws, size_t ws_size,
                              hipStream_t stream) {
  (void)in_sizes; (void)n_in; (void)out_size; (void)ws_size;

  const int di[6] = {2,4,7,10,13,16};
  const int fi6[6] = {-1,5,8,11,14,17};
  const int ti[6] = {3,6,9,12,15,18};

  const int midv[6]={45,96,192,384,768,1536};
  const int midp[6]={0,128,256,384,768,1536};
  const int cinv[6]={0,64,128,256,512,1024};
  const int coutv[6]={64,128,256,512,1024,2048};
  const int tkv[6]={1,3,3,3,3,1};
  const int Nv[6]={2048,1024,512,512,256,256};
  const int mv[6]={1024,512,512,256,256,128};
  const int Lv[6]={4,4,2,2,1,1};
  const int Tv[6]={4,2,2,1,1,1};
  const float rrv[6]={1.5f,3.f,3.f,6.f,6.f,6.f};

  float* ws=(float*)d_ws;
  size_t off=0;
  auto A=[&](size_t n)->float*{ float* p=ws+off; off+=(n+63)&~(size_t)63; return p; };
  auto Ah=[&](size_t n)->f16*{ return (f16*)A((n+1)/2); };

  int* flag=(int*)A(64);

  f16* W2h[6]; W2h[0]=nullptr;
  for(int l=1;l<6;l++) W2h[l]=Ah((size_t)midp[l]*3*cinv[l]);
  f16* Wth[6]; Wth[0]=nullptr;
  for(int l=1;l<6;l++) Wth[l]=Ah((size_t)coutv[l]*tkv[l]*midv[l]);  // Wth[5] slot holds t5T (transposed)
  float* Wd0=A(135);
  float* Wt0=A(2880);
  f16* fcwh=Ah(2097152);
  float* fcb=A(1024);
  f16* Wp=Ah(1572864);             // W' = fcw @ Wt5 : [1024][1536]

  float* X[7];
  X[0]=A(786432);
  for(int l=0;l<6;l++) X[l+1]=A((size_t)32*Tv[l]*mv[l]*3);

  f16* FA=Ah(8388608);
  f16* FB=Ah(8388608);
  f16* F[7]; F[0]=nullptr;
  for(int l=0;l<6;l++) F[l+1]=(l%2==0)?FA:FB;

  f16* nfh=Ah(18874368);
  float* sumsAll=A(11*4608);
  f16* Gh=Ah(25165824);
  int* bqA=(int*)A(1179648);
  int* bqB=(int*)A(1179648);
  int* bqBuf[2]={bqA,bqB};

  // ---- setup: detect+zero (1 dispatch); all converts ride inside fps0m
  {
    int zn=11*4608;
    int zb=(zn+255)/256;
    k_detect<<<dim3(1+zb),dim3(256),0,stream>>>((const unsigned int*)d_in[0], 4096, flag, sumsAll, zn);
  }

  CvtF32 J32; int bp32=0;
  {
    J32.src[0]=d_in[0];  J32.dst[0]=X[0];  J32.n[0]=786432;
    J32.src[1]=d_in[3];  J32.dst[1]=Wt0;   J32.n[1]=2880;
    J32.src[2]=d_in[20]; J32.dst[2]=fcb;   J32.n[2]=1024;
    J32.src[3]=d_in[2];  J32.dst[3]=Wd0;   J32.n[3]=135;
    for(int j2=0;j2<4;j2++){ J32.blk0[j2]=bp32; bp32+=(J32.n[j2]+255)/256; }
    J32.blk0[4]=bp32;
  }
  CvtF16 J16; int bp16=0;
  {
    int ns[6]={36864,147456,589824,2359296,3145728,2097152};
    const void* ss[6]={d_in[ti[1]],d_in[ti[2]],d_in[ti[3]],d_in[ti[4]],d_in[ti[5]],d_in[19]};
    f16* ds[6]={Wth[1],Wth[2],Wth[3],Wth[4],Wth[5],fcwh};   // ds[4] written TRANSPOSED (t5T)
    for(int j2=0;j2<6;j2++){ J16.src[j2]=ss[j2]; J16.dst[j2]=ds[j2]; J16.n[j2]=ns[j2]; J16.blk0[j2]=bp16; bp16+=(ns[j2]+255)/256; }
    J16.blk0[6]=bp16;
  }
  W2J JW; int bpw2=0;
  {
    for(int l=1;l<6;l++){
      int j2=l-1;
      JW.wd[j2]=d_in[di[l]]; JW.wf[j2]=d_in[fi6[l]]; JW.dst[j2]=W2h[l];
      JW.mid[j2]=midv[l]; JW.cin[j2]=cinv[l]; JW.n[j2]=midp[l]*3*cinv[l];
      JW.blk0[j2]=bpw2; bpw2+=(JW.n[j2]+255)/256;
    }
    JW.blk0[5]=bpw2;
  }

  // ---- schedule tables
  const int SLOTS[6]={4,5,4,2,1,1};
  const int sTT[6][5]={{0,1,2,3,0},{0,0,1,1,1},{0,0,1,1,0},{0,0,0,0,0},{0,0,0,0,0},{0,0,0,0,0}};
  const int sFI[6][5]={{0,1,2,3,0},{0,1,1,2,3},{0,1,0,1,0},{0,1,0,0,0},{0,0,0,0,0},{0,0,0,0,0}};
  const int sJJ[6][5]={{0,0,0,0,0},{1,2,0,1,2},{1,2,0,1,0},{1,2,0,0,0},{1,0,0,0,0},{0,0,0,0,0}};
  const int4 jm4l0={1,1,1,1};
  const int Tcenters[6][4]={{0,1,2,3},{0,2,0,0},{0,1,0,0},{0,0,0,0},{0,0,0,0},{0,0,0,0}};
  const int slotBase[6]={0,4,6,8,9,10};

  Sched Sl[6];
  for(int l=0;l<6;l++)
    for(int s=0;s<5;s++){ Sl[l].tt[s]=sTT[l][s]; Sl[l].fi[s]=sFI[l][s]; Sl[l].jj[s]=sJJ[l][s]; }

  auto bqGeo=[&](int lb, int& bqN, int& chunks){
    chunks=(mv[lb]+255)>>8;
    bqN=SLOTS[lb]*32*chunks;
  };

  // FPS_0 merged with ALL converts (reads raw input via ldmix)
  k_fps0m<<<dim3((unsigned)(128+bp32+bp16+bpw2)),dim3(256),0,stream>>>(
      d_in[0],X[1],J32,J16,JW,flag,bp32,bp16);

  // pre-loop merged: [FPS_1 || bq_0 -> bqA || W' GEMM]
  {
    int bqN,chunks; bqGeo(0,bqN,chunks);
    int fpsN=32*Tv[1];
    k_mega<4,true><<<dim3((unsigned)(fpsN+bqN+96)),dim3(256),0,stream>>>(
        X[1],Lv[1],Nv[1],mv[1],Tcenters[1][0],Tcenters[1][1],Tcenters[1][2],Tcenters[1][3],Tv[1],X[2],fpsN,
        0,0, FA,X[0],X[1],bqA,nfh,mv[0],1,Nv[0],Lv[0],(size_t)Tv[0]*mv[0]*3,32*mv[0],Sl[0],Wd0,1,1,
        X[0],X[1],bqBuf[0],Nv[0],mv[0],rrv[0]*rrv[0],Lv[0],(size_t)Tv[0]*mv[0]*3,32*mv[0],Sl[0],chunks,bqN,
        fcwh,Wth[5],Wp);
  }

  for(int l=0;l<6;l++){
    int N=Nv[l], m=mv[l], Lin=Lv[l], T=Tv[l], cin=cinv[l], mid=midv[l];
    int C=tkv[l]*midv[l], M=32*m, cout=coutv[l];
    size_t aBS=(size_t)T*m*3;
    float* sumsL=sumsAll+(size_t)slotBase[l]*4608;

    if(l<5){
      int lb=l+1;
      int bqN,chunksB; bqGeo(lb,bqN,chunksB);
      size_t aBSB=(size_t)Tv[lb]*mv[lb]*3;
      int MB=32*mv[lb];
      int oN, isP0;
      if(l==0){ isP0=1; oN=M; }
      else{
        isP0=0;
        int cw2=cin>>1; if(cw2>256) cw2=256;
        int rpb=256/cw2;
        oN=SLOTS[l]*M/rpb;
      }
      const f16* featsO=(l==0)?FA:F[l];
      f16* GoN=(l==0)?nfh:Gh;
      int fpsN=0, lf=l+2;
      if(lf<=5) fpsN=32*Tv[lf];
      int a0=0,a1=0,a2=0,a3=0;
      if(lf<=5){ a0=Tcenters[lf][0]; a1=Tcenters[lf][1]; a2=Tcenters[lf][2]; a3=Tcenters[lf][3]; }
      const float* xyzF=(lf<=5)?X[lf]:X[5];
      float* ancOut=(lf<=5)?X[lf+1]:X[6];
      int Lf=(lf<=5)?Lv[lf]:1, Nf=(lf<=5)?Nv[lf]:256, mf=(lf<=5)?mv[lf]:1, Tf=(lf<=5)?Tv[lf]:1;
      dim3 g((unsigned)(fpsN+oN+bqN)), blk(256);
      if(lf<=5 && Nv[lf]==512)
        k_mega<2,false><<<g,blk,0,stream>>>(xyzF,Lf,Nf,mf,a0,a1,a2,a3,Tf,ancOut,fpsN,
            oN,isP0, featsO,X[l],X[l+1],bqBuf[l&1],GoN,m,cin,N,Lin,aBS,M,Sl[l],Wd0,mid,C,
            X[lb],X[lb+1],bqBuf[lb&1],Nv[lb],mv[lb],rrv[lb]*rrv[lb],Lv[lb],aBSB,MB,Sl[lb],chunksB,bqN,
            nullptr,nullptr,nullptr);
      else
        k_mega<1,false><<<g,blk,0,stream>>>(xyzF,Lf,Nf,mf,a0,a1,a2,a3,Tf,ancOut,fpsN,
            oN,isP0, featsO,X[l],X[l+1],bqBuf[l&1],GoN,m,cin,N,Lin,aBS,M,Sl[l],Wd0,mid,C,
            X[lb],X[lb+1],bqBuf[lb&1],Nv[lb],mv[lb],rrv[lb]*rrv[lb],Lv[lb],aBSB,MB,Sl[lb],chunksB,bqN,
            nullptr,nullptr,nullptr);
    } else {
      int cw2=cin>>1; if(cw2>256) cw2=256;
      int rpb=256/cw2;
      k_outer<<<dim3((unsigned)(SLOTS[l]*M/rpb)),256,0,stream>>>(
          F[l],X[l],X[l+1],bqBuf[l&1],Gh,m,cin,N,Lin,aBS,N-1,M,Sl[l]);
    }

    if(l>=1)
      k_pg<<<dim3((unsigned)(SLOTS[l]*M/128),(unsigned)(midp[l]/128)),256,0,stream>>>(
          Gh,W2h[l],nfh,3*cin,mid,C,M,Sl[l],sumsL,4608);
    else
      k_bnstat<<<dim3((C+255)/256,32,T),256,0,stream>>>(nfh,M,C,sumsL,mid,jm4l0,4608);

    size_t oBS=(size_t)T*m*cout;
    size_t ttO=(size_t)m*cout;
    float invM=1.0f/(float)M;
    if(l==0)
      k_gemm0<<<dim3(M/64,1,4),256,0,stream>>>(nfh,Wt0,F[1],M,C,cout,m,oBS,ttO,sumsL,4608,invM);
    else if(l<5)
      k_gemm_mfma<true,false,true><<<dim3(M/128,cout/128,T),256,0,stream>>>(
          nfh,Wth[l],nullptr,F[l+1],C,cout,m,oBS,(size_t)M*C,ttO,nullptr,sumsL,4608,invM);
    else
      // FC' : telescoped (gemm_5 + FC) = BN+ReLU(nfh_5) @ W'^T + fcb -> d_out
      k_gemm_mfma<false,true,true><<<dim3(M/128,1024/128,1),256,0,stream>>>(
          nfh,Wp,fcb,d_out,C,1024,m,(size_t)m*1024,0,0,flag,sumsL,4608,invM);
  }
}